// Round 7
// baseline (529.670 us; speedup 1.0000x reference)
//
#include <hip/hip_runtime.h>

// ---------------- problem constants ----------------
#define CCH   256
#define HH    96
#define WW    96
#define HO    94
#define LL    8836        // 94*94 patches
#define DD    2304        // 256*9
#define LPAD  8960        // 35 * 256

// GEMM geometry: 256x256 tile, 8 waves (2M x 4N), 512 threads.
// K in 72 kk-slices of 32; LDS = ring of 4 (A+B) slices, 128 KiB.
#define BM2   256
#define NT2   35          // 8960/256
#define NPH   72          // 2304/32
#define ASL   8192        // elements per slice half-pair (256*32)
#define BBASE 32768       // B slices start (elements)

typedef unsigned short ushort_t;
typedef unsigned long long u64;

using short8 = __attribute__((ext_vector_type(8))) short;
using f32x4  = __attribute__((ext_vector_type(4))) float;

// ---------------- workspace layout (bytes) ----------------
#define OFF_B     41287680ull
#define OFF_RNB   82575360ull
#define OFF_N2B   82611200ull
#define OFF_W2X   82647040ull
#define OFF_P2    82682880ull
#define OFF_BEST  82756608ull

__device__ __forceinline__ ushort_t f2bf(float f) {
    unsigned u = __float_as_uint(f);
    unsigned r = (u + 0x7FFFu + ((u >> 16) & 1u)) >> 16;  // RNE
    return (ushort_t)r;
}

__device__ __forceinline__ void gload16(const ushort_t* g, ushort_t* l) {
    __builtin_amdgcn_global_load_lds(
        (const __attribute__((address_space(1))) unsigned int*)g,
        (__attribute__((address_space(3))) unsigned int*)l,
        16, 0, 0);
}

// ---- 1: per-pixel channel sum of squares for both images ----
__global__ __launch_bounds__(256) void k_chan_sumsq(const float* __restrict__ st,
                                                    const float* __restrict__ x,
                                                    float* __restrict__ P2) {
    int p = blockIdx.x * 256 + threadIdx.x;
    if (p >= 2 * HH * WW) return;
    const float* img = (p < HH * WW) ? st : x;
    int pp = (p < HH * WW) ? p : p - HH * WW;
    float s = 0.f;
#pragma unroll 4
    for (int c = 0; c < CCH; ++c) {
        float v = img[c * (HH * WW) + pp];
        s += v * v;
    }
    P2[p] = s;
}

// ---- 2: 3x3 window sums -> style inv-norms, style norm^2, x patch norm^2 ----
__global__ __launch_bounds__(256) void k_win(const float* __restrict__ P2,
                                             float* __restrict__ rnB,
                                             float* __restrict__ n2B,
                                             float* __restrict__ win2x) {
    int i = blockIdx.x * 256 + threadIdx.x;
    if (i >= LL) return;
    int y = i / HO, xc = i % HO;
    float ss = 0.f, sx = 0.f;
#pragma unroll
    for (int kh = 0; kh < 3; ++kh)
#pragma unroll
        for (int kw = 0; kw < 3; ++kw) {
            int off = (y + kh) * WW + xc + kw;
            ss += P2[off];
            sx += P2[HH * WW + off];
        }
    rnB[i] = 1.f / (sqrtf(ss) + 1e-8f);
    n2B[i] = ss;
    win2x[i] = sx;
}

// ---- 3: pack patches to bf16 [LPAD][DD]; A = raw x, B = normalized style ----
__global__ __launch_bounds__(256) void k_pack(const float* __restrict__ x,
                                              const float* __restrict__ st,
                                              const float* __restrict__ rnB,
                                              ushort_t* __restrict__ A,
                                              ushort_t* __restrict__ Bm) {
    int row = blockIdx.x;
    bool isB = row >= LPAD;
    int i = isB ? row - LPAD : row;
    ushort_t* dst = (isB ? Bm : A) + (size_t)i * DD + threadIdx.x * 9;
    if (i >= LL) {
#pragma unroll
        for (int k = 0; k < 9; ++k) dst[k] = 0;
        return;
    }
    int y = i / HO, xc = i % HO;
    const float* src = isB ? st : x;
    float scale = isB ? rnB[i] : 1.f;
    const float* base = src + (size_t)threadIdx.x * (HH * WW) + y * WW + xc;
#pragma unroll
    for (int kh = 0; kh < 3; ++kh)
#pragma unroll
        for (int kw = 0; kw < 3; ++kw)
            dst[kh * 3 + kw] = f2bf(base[kh * WW + kw] * scale);
}

// ---- 4: fused GEMM (A * B^T) + per-row argmax ----
// Pipelined body (reads s+1, MFMA s) with sched_group_barrier-pinned
// fine interleave: 4 x {3 ds_read, 4 MFMA, 1 VMEM, 4 MFMA} per body.
__global__ __launch_bounds__(512, 2) void k_gemm2(const ushort_t* __restrict__ A,
                                                  const ushort_t* __restrict__ Bm,
                                                  u64* __restrict__ best) {
    extern __shared__ __align__(16) ushort_t lds[];  // 128 KiB

    const int t = threadIdx.x;
    const int wid = t >> 6, lane = t & 63;
    const int wr = wid >> 2, wc = wid & 3;
    const int l15 = lane & 15, l4 = lane >> 4;

    // T1: bijective XCD swizzle (m204), nwg = 1225
    const int nwg = NT2 * NT2;
    const int q = nwg >> 3, r = nwg & 7;  // 153, 1
    const int bid = blockIdx.x;
    const int xcd = bid & 7, loc = bid >> 3;
    const int swz = ((xcd < r) ? xcd * (q + 1) : r * (q + 1) + (xcd - r) * q) + loc;
    const int it = swz / NT2, jt = swz % NT2;

    // staging source (pre-swizzled k-group: (c&3)^((c>>3)&3))
    const int gsrc = (t & 3) ^ ((t >> 3) & 3);
    const ushort_t* pA0 = A  + (size_t)(it * BM2 + (t >> 2)) * DD + gsrc * 8;
    const ushort_t* pB0 = Bm + (size_t)(jt * BM2 + (t >> 2)) * DD + gsrc * 8;

    // fragment read offsets (swizzled): phys group = l4 ^ ((row>>1)&3)
    const int sp8 = (l4 ^ ((l15 >> 1) & 3)) * 8;
    int aoff[8], boff[4];
#pragma unroll
    for (int mi = 0; mi < 8; ++mi)
        aoff[mi] = (wr * 128 + mi * 16 + l15) * 32 + sp8;
#pragma unroll
    for (int ni = 0; ni < 4; ++ni)
        boff[ni] = (wc * 64 + ni * 16 + l15) * 32 + sp8;

    f32x4 acc[8][4];
#pragma unroll
    for (int mi = 0; mi < 8; ++mi)
#pragma unroll
        for (int ni = 0; ni < 4; ++ni)
            acc[mi][ni] = (f32x4){0.f, 0.f, 0.f, 0.f};

    // prologue: stage slices 0,1,2
#define PSTAGE(S)                                                            \
    do {                                                                     \
        const ushort_t* sa = pA0 + (size_t)(S) * 32;                         \
        const ushort_t* sb = pB0 + (size_t)(S) * 32;                         \
        gload16(sa,          lds + (S) * ASL + t * 8);                       \
        gload16(sa + 294912, lds + (S) * ASL + 4096 + t * 8);                \
        gload16(sb,          lds + BBASE + (S) * ASL + t * 8);               \
        gload16(sb + 294912, lds + BBASE + (S) * ASL + 4096 + t * 8);        \
    } while (0)
    PSTAGE(0); PSTAGE(1); PSTAGE(2);
#undef PSTAGE
    asm volatile("s_waitcnt vmcnt(4)" ::: "memory");  // slices 0 AND 1 landed
    __builtin_amdgcn_sched_barrier(0);
    __builtin_amdgcn_s_barrier();

    short8 afX[8], bfX[4], afY[8], bfY[4];
    // X <- slice 0 fragments
#pragma unroll
    for (int ni = 0; ni < 4; ++ni)
        bfX[ni] = *(const short8*)(lds + BBASE + boff[ni]);
#pragma unroll
    for (int mi = 0; mi < 8; ++mi)
        afX[mi] = *(const short8*)(lds + aoff[mi]);

// BODY(s): issue reads for s+1 into NXT + stage s+3 + MFMA s from CUR,
// emitted as a fine interleave via sched_group_barrier; one barrier.
#define BODY(S, CA, CB, NA, NB)                                              \
    {                                                                        \
        const int s_ = (S);                                                  \
        const ushort_t* rb = lds + ((s_ + 1) & 3) * ASL;                     \
        _Pragma("unroll")                                                    \
        for (int ni = 0; ni < 4; ++ni)                                       \
            NB[ni] = *(const short8*)(rb + BBASE + boff[ni]);                \
        _Pragma("unroll")                                                    \
        for (int mi = 0; mi < 8; ++mi)                                       \
            NA[mi] = *(const short8*)(rb + aoff[mi]);                        \
        {                                                                    \
            const int ss = (s_ + 3 > NPH - 1) ? (NPH - 1) : (s_ + 3);        \
            const ushort_t* sa = pA0 + (size_t)ss * 32;                      \
            const ushort_t* sb = pB0 + (size_t)ss * 32;                      \
            ushort_t* da = lds + ((s_ + 3) & 3) * ASL + t * 8;               \
            gload16(sa,          da);                                        \
            gload16(sa + 294912, da + 4096);                                 \
            gload16(sb,          da + BBASE);                                \
            gload16(sb + 294912, da + BBASE + 4096);                         \
        }                                                                    \
        __builtin_amdgcn_s_setprio(1);                                       \
        _Pragma("unroll")                                                    \
        for (int mi = 0; mi < 8; ++mi)                                       \
            _Pragma("unroll")                                                \
            for (int ni = 0; ni < 4; ++ni)                                   \
                acc[mi][ni] = __builtin_amdgcn_mfma_f32_16x16x32_bf16(       \
                    CA[mi], CB[ni], acc[mi][ni], 0, 0, 0);                   \
        __builtin_amdgcn_s_setprio(0);                                       \
        /* pin interleave: 4 x {3 ds_read, 4 MFMA, 1 vmem, 4 MFMA} */        \
        _Pragma("unroll")                                                    \
        for (int g_ = 0; g_ < 4; ++g_) {                                     \
            __builtin_amdgcn_sched_group_barrier(0x100, 3, 0);               \
            __builtin_amdgcn_sched_group_barrier(0x008, 4, 0);               \
            __builtin_amdgcn_sched_group_barrier(0x010, 1, 0);               \
            __builtin_amdgcn_sched_group_barrier(0x008, 4, 0);               \
        }                                                                    \
        asm volatile("s_waitcnt vmcnt(4)" ::: "memory");                     \
        __builtin_amdgcn_sched_barrier(0);                                   \
        __builtin_amdgcn_s_barrier();                                        \
    }

    for (int s2 = 0; s2 < NPH - 2; s2 += 2) {
        BODY(s2,     afX, bfX, afY, bfY)
        BODY(s2 + 1, afY, bfY, afX, bfX)
    }
    BODY(NPH - 2, afX, bfX, afY, bfY)   // body 70: reads slice 71 into Y
#undef BODY
    // tail body 71: MFMA from Y (compiler inserts lgkm wait)
    __builtin_amdgcn_s_setprio(1);
#pragma unroll
    for (int mi = 0; mi < 8; ++mi)
#pragma unroll
        for (int ni = 0; ni < 4; ++ni)
            acc[mi][ni] = __builtin_amdgcn_mfma_f32_16x16x32_bf16(
                afY[mi], bfY[ni], acc[mi][ni], 0, 0, 0);
    __builtin_amdgcn_s_setprio(0);

    // epilogue: per output row, max over this block's 256 j's, merge globally
    const int jbase = jt * BM2 + wc * 64 + l15;
#pragma unroll
    for (int mi = 0; mi < 8; ++mi) {
#pragma unroll
        for (int rr = 0; rr < 4; ++rr) {
            float bv = -3.4e38f;
            int bj = 0x7FFFFFFF;
#pragma unroll
            for (int ni = 0; ni < 4; ++ni) {
                int j = jbase + ni * 16;
                float v = acc[mi][ni][rr];
                if (j < LL && (v > bv || (v == bv && j < bj))) { bv = v; bj = j; }
            }
#pragma unroll
            for (int m = 1; m < 16; m <<= 1) {
                float ov = __shfl_xor(bv, m, 64);
                int oj = __shfl_xor(bj, m, 64);
                if (ov > bv || (ov == bv && oj < bj)) { bv = ov; bj = oj; }
            }
            if (l15 == 0) {
                int i = it * BM2 + wr * 128 + mi * 16 + l4 * 4 + rr;
                if (i < LL) {
                    unsigned u = __float_as_uint(bv);
                    unsigned s = (bv < 0.f) ? ~u : (u | 0x80000000u);
                    u64 packed = ((u64)s << 32) | (unsigned)(~(unsigned)bj);
                    atomicMax(&best[i], packed);
                }
            }
        }
    }
}

// ---- 5: final scalar ----
__global__ __launch_bounds__(256) void k_final(const u64* __restrict__ best,
                                               const float* __restrict__ rnB,
                                               const float* __restrict__ n2B,
                                               const float* __restrict__ win2x,
                                               float* __restrict__ out) {
    int i = blockIdx.x * 256 + threadIdx.x;
    float contrib = 0.f;
    if (i < LL) {
        u64 p = best[i];
        unsigned s = (unsigned)(p >> 32);
        unsigned ub = (s & 0x80000000u) ? (s & 0x7FFFFFFFu) : ~s;
        float bv = __uint_as_float(ub);
        int j = (int)(~(unsigned)(p & 0xFFFFFFFFull));
        float dot = bv / rnB[j];
        contrib = win2x[i] + n2B[j] - 2.f * dot;
    }
    float sred = contrib;
#pragma unroll
    for (int o = 32; o > 0; o >>= 1) sred += __shfl_down(sred, o, 64);
    __shared__ float red[4];
    if ((threadIdx.x & 63) == 0) red[threadIdx.x >> 6] = sred;
    __syncthreads();
    if (threadIdx.x == 0) {
        float tot = red[0] + red[1] + red[2] + red[3];
        atomicAdd(out, tot * (1.0f / ((float)DD * (float)LL)));
    }
}

extern "C" void kernel_launch(void* const* d_in, const int* in_sizes, int n_in,
                              void* d_out, int out_size, void* d_ws, size_t ws_size,
                              hipStream_t stream) {
    const float* x  = (const float*)d_in[0];
    const float* st = (const float*)d_in[1];
    char* ws = (char*)d_ws;

    ushort_t* A    = (ushort_t*)ws;
    ushort_t* Bm   = (ushort_t*)(ws + OFF_B);
    float* rnB     = (float*)(ws + OFF_RNB);
    float* n2B     = (float*)(ws + OFF_N2B);
    float* win2x   = (float*)(ws + OFF_W2X);
    float* P2      = (float*)(ws + OFF_P2);
    u64* best      = (u64*)(ws + OFF_BEST);
    float* out     = (float*)d_out;

    hipFuncSetAttribute((const void*)k_gemm2,
                        hipFuncAttributeMaxDynamicSharedMemorySize, 131072);

    hipMemsetAsync(best, 0, (size_t)LL * 8, stream);
    hipMemsetAsync(out, 0, sizeof(float), stream);

    k_chan_sumsq<<<dim3(72), dim3(256), 0, stream>>>(st, x, P2);
    k_win<<<dim3(35), dim3(256), 0, stream>>>(P2, rnB, n2B, win2x);
    k_pack<<<dim3(2 * LPAD), dim3(256), 0, stream>>>(x, st, rnB, A, Bm);
    k_gemm2<<<dim3(NT2 * NT2), dim3(512), 131072, stream>>>(A, Bm, best);
    k_final<<<dim3(35), dim3(256), 0, stream>>>(best, rnB, n2B, win2x, out);
}

// Round 8
// 400.280 us; speedup vs baseline: 1.3232x; 1.3232x over previous
//
#include <hip/hip_runtime.h>

// ---------------- problem constants ----------------
#define CCH   256
#define HH    96
#define WW    96
#define HO    94
#define LL    8836        // 94*94 patches
#define DD    2304        // 256*9 elements (1 byte each, i8)
#define LPAD  8960        // 35 * 256

// GEMM geometry: 256x256 tile, 8 waves (2M x 4N), 512 threads, i8 K=64 MFMA.
// K in 36 slices of 64 (64 B per row per slice); LDS ring of 4 (A+B) slices.
#define BM2   256
#define NT2   35          // 8960/256
#define NPH   36          // 2304/64
#define ASLB  16384       // bytes per slice (256 rows x 64 B)
#define BBASEB 65536      // B slices start (bytes)

typedef unsigned char u8;
typedef unsigned long long u64;

using i32x4 = __attribute__((ext_vector_type(4))) int;

// ---------------- workspace layout (bytes) ----------------
// Aq u8[LPAD][2304] : 0 .. 20,643,840
// Bq u8[LPAD][2304] : 20,643,840 .. 41,287,680
// then float arrays [LL] (35840 B each), P2/PM (73728 each), best (71680)
#define OFF_BQ    20643840ull
#define OFF_RNB   41287680ull
#define OFF_N2B   41323520ull
#define OFF_W2X   41359360ull
#define OFF_QSA   41395200ull
#define OFF_QSB   41431040ull
#define OFF_COLS  41466880ull
#define OFF_SAF   41502720ull
#define OFF_P2    41538560ull
#define OFF_PM    41612288ull
#define OFF_BEST  41686016ull

__device__ __forceinline__ void gload16(const void* g, void* l) {
    __builtin_amdgcn_global_load_lds(
        (const __attribute__((address_space(1))) unsigned int*)g,
        (__attribute__((address_space(3))) unsigned int*)l,
        16, 0, 0);
}

// ---- 1: per-pixel channel sum-of-squares and abs-max for both images ----
__global__ __launch_bounds__(256) void k_chan_stats(const float* __restrict__ st,
                                                    const float* __restrict__ x,
                                                    float* __restrict__ P2,
                                                    float* __restrict__ PM) {
    int p = blockIdx.x * 256 + threadIdx.x;
    if (p >= 2 * HH * WW) return;
    const float* img = (p < HH * WW) ? st : x;
    int pp = (p < HH * WW) ? p : p - HH * WW;
    float s = 0.f, m = 0.f;
#pragma unroll 4
    for (int c = 0; c < CCH; ++c) {
        float v = img[c * (HH * WW) + pp];
        s += v * v;
        m = fmaxf(m, fabsf(v));
    }
    P2[p] = s;
    PM[p] = m;
}

// ---- 2: 3x3 window reductions -> norms and quantizer scales ----
__global__ __launch_bounds__(256) void k_win(const float* __restrict__ P2,
                                             const float* __restrict__ PM,
                                             float* __restrict__ rnB,
                                             float* __restrict__ n2B,
                                             float* __restrict__ win2x,
                                             float* __restrict__ qsA,
                                             float* __restrict__ qsB,
                                             float* __restrict__ colS,
                                             float* __restrict__ sAf) {
    int i = blockIdx.x * 256 + threadIdx.x;
    if (i >= LL) return;
    int y = i / HO, xc = i % HO;
    float ss = 0.f, sx = 0.f, ms = 0.f, mx = 0.f;
#pragma unroll
    for (int kh = 0; kh < 3; ++kh)
#pragma unroll
        for (int kw = 0; kw < 3; ++kw) {
            int off = (y + kh) * WW + xc + kw;
            ss += P2[off];
            sx += P2[HH * WW + off];
            ms = fmaxf(ms, PM[off]);
            mx = fmaxf(mx, PM[HH * WW + off]);
        }
    float rn = 1.f / (sqrtf(ss) + 1e-8f);
    float msc = fmaxf(ms, 1e-30f), mxc = fmaxf(mx, 1e-30f);
    rnB[i] = rn;
    n2B[i] = ss;
    win2x[i] = sx;
    qsA[i] = 127.f / mxc;                  // x quantizer
    qsB[i] = 127.f / msc;                  // style quantizer
    colS[i] = rn * msc * (1.f / 127.f);    // per-column argmax scale (= sB*rnB)
    sAf[i] = mxc * (1.f / 127.f);          // row dequant scale (= sA)
}

// ---- 3: quantize patches to i8 [LPAD][2304]; A = x, B = raw style ----
__global__ __launch_bounds__(256) void k_pack(const float* __restrict__ x,
                                              const float* __restrict__ st,
                                              const float* __restrict__ qsA,
                                              const float* __restrict__ qsB,
                                              u8* __restrict__ Aq,
                                              u8* __restrict__ Bq) {
    int row = blockIdx.x;
    bool isB = row >= LPAD;
    int i = isB ? row - LPAD : row;
    u8* dst = (isB ? Bq : Aq) + (size_t)i * DD + threadIdx.x * 9;
    if (i >= LL) {
#pragma unroll
        for (int k = 0; k < 9; ++k) dst[k] = 0;
        return;
    }
    int y = i / HO, xc = i % HO;
    const float* src = isB ? st : x;
    float scale = isB ? qsB[i] : qsA[i];
    const float* base = src + (size_t)threadIdx.x * (HH * WW) + y * WW + xc;
#pragma unroll
    for (int kh = 0; kh < 3; ++kh)
#pragma unroll
        for (int kw = 0; kw < 3; ++kw) {
            int q = (int)rintf(base[kh * WW + kw] * scale);
            dst[kh * 3 + kw] = (u8)q;
        }
}

// ---- 4: fused i8 GEMM (A * B^T) + per-row scaled argmax ----
__global__ __launch_bounds__(512, 2) void k_gemm2(const u8* __restrict__ A,
                                                  const u8* __restrict__ Bm,
                                                  const float* __restrict__ colS,
                                                  u64* __restrict__ best) {
    extern __shared__ __align__(16) u8 lds[];  // 128 KiB

    const int t = threadIdx.x;
    const int wid = t >> 6, lane = t & 63;
    const int wr = wid >> 2, wc = wid & 3;
    const int l15 = lane & 15, l4 = lane >> 4;

    // T1: bijective XCD swizzle (m204), nwg = 1225
    const int nwg = NT2 * NT2;
    const int q = nwg >> 3, r = nwg & 7;  // 153, 1
    const int bid = blockIdx.x;
    const int xcd = bid & 7, loc = bid >> 3;
    const int swz = ((xcd < r) ? xcd * (q + 1) : r * (q + 1) + (xcd - r) * q) + loc;
    const int it = swz / NT2, jt = swz % NT2;

    // staging source (pre-swizzled 16B k-group: (c&3)^((c>>3)&3))
    const int gsrc = (t & 3) ^ ((t >> 3) & 3);
    const u8* pA0 = A  + (size_t)(it * BM2 + (t >> 2)) * DD + gsrc * 16;
    const u8* pB0 = Bm + (size_t)(jt * BM2 + (t >> 2)) * DD + gsrc * 16;

    // fragment read offsets (swizzled): phys 16B-group = l4 ^ ((row>>1)&3)
    const int sp16 = (l4 ^ ((l15 >> 1) & 3)) * 16;
    int aoff[8], boff[4];
#pragma unroll
    for (int mi = 0; mi < 8; ++mi)
        aoff[mi] = (wr * 128 + mi * 16 + l15) * 64 + sp16;
#pragma unroll
    for (int ni = 0; ni < 4; ++ni)
        boff[ni] = BBASEB + (wc * 64 + ni * 16 + l15) * 64 + sp16;

    i32x4 acc[8][4];
#pragma unroll
    for (int mi = 0; mi < 8; ++mi)
#pragma unroll
        for (int ni = 0; ni < 4; ++ni)
            acc[mi][ni] = (i32x4){0, 0, 0, 0};

    // prologue: stage slices 0,1,2
#define PSTAGE(S)                                                            \
    do {                                                                     \
        const u8* sa = pA0 + (size_t)(S) * 64;                               \
        const u8* sb = pB0 + (size_t)(S) * 64;                               \
        gload16(sa,          lds + (S) * ASLB + t * 16);                     \
        gload16(sa + 294912, lds + (S) * ASLB + 8192 + t * 16);              \
        gload16(sb,          lds + BBASEB + (S) * ASLB + t * 16);            \
        gload16(sb + 294912, lds + BBASEB + (S) * ASLB + 8192 + t * 16);     \
    } while (0)
    PSTAGE(0); PSTAGE(1); PSTAGE(2);
#undef PSTAGE
    asm volatile("s_waitcnt vmcnt(8)" ::: "memory");  // slice 0 landed
    __builtin_amdgcn_sched_barrier(0);
    __builtin_amdgcn_s_barrier();

    i32x4 af03[4], af47[4], bfr[4];

// SUB-A: 8 ds_reads (bfr + af03) | stage A-half of slice kb+U+3 | 16 MFMA m0-3
#define SUBA(U)                                                              \
    {                                                                        \
        _Pragma("unroll")                                                    \
        for (int ni = 0; ni < 4; ++ni)                                       \
            bfr[ni] = *(const i32x4*)(lds + (U) * ASLB + boff[ni]);          \
        _Pragma("unroll")                                                    \
        for (int mi = 0; mi < 4; ++mi)                                       \
            af03[mi] = *(const i32x4*)(lds + (U) * ASLB + aoff[mi]);         \
        {                                                                    \
            const int ss = (kb + (U) + 3 > NPH - 1) ? (NPH - 1) : (kb + (U) + 3); \
            const u8* sa = pA0 + (size_t)ss * 64;                            \
            u8* da = lds + (((U) + 3) & 3) * ASLB + t * 16;                  \
            gload16(sa,          da);                                        \
            gload16(sa + 294912, da + 8192);                                 \
        }                                                                    \
        __builtin_amdgcn_s_barrier();                                        \
        asm volatile("s_waitcnt lgkmcnt(0)" ::: "memory");                   \
        __builtin_amdgcn_sched_barrier(0);                                   \
        __builtin_amdgcn_s_setprio(1);                                       \
        _Pragma("unroll")                                                    \
        for (int mi = 0; mi < 4; ++mi)                                       \
            _Pragma("unroll")                                                \
            for (int ni = 0; ni < 4; ++ni)                                   \
                acc[mi][ni] = __builtin_amdgcn_mfma_i32_16x16x64_i8(         \
                    af03[mi], bfr[ni], acc[mi][ni], 0, 0, 0);                \
        __builtin_amdgcn_s_setprio(0);                                       \
        __builtin_amdgcn_s_barrier();                                        \
    }

// SUB-B: 4 ds_reads (af47) | stage B-half | vmcnt(8) | 16 MFMA m4-7 (bfr reuse)
#define SUBB(U)                                                              \
    {                                                                        \
        _Pragma("unroll")                                                    \
        for (int mi = 0; mi < 4; ++mi)                                       \
            af47[mi] = *(const i32x4*)(lds + (U) * ASLB + aoff[4 + mi]);     \
        {                                                                    \
            const int ss = (kb + (U) + 3 > NPH - 1) ? (NPH - 1) : (kb + (U) + 3); \
            const u8* sb = pB0 + (size_t)ss * 64;                            \
            u8* db = lds + BBASEB + (((U) + 3) & 3) * ASLB + t * 16;         \
            gload16(sb,          db);                                        \
            gload16(sb + 294912, db + 8192);                                 \
        }                                                                    \
        asm volatile("s_waitcnt vmcnt(8)" ::: "memory");                     \
        __builtin_amdgcn_sched_barrier(0);                                   \
        __builtin_amdgcn_s_barrier();                                        \
        asm volatile("s_waitcnt lgkmcnt(0)" ::: "memory");                   \
        __builtin_amdgcn_sched_barrier(0);                                   \
        __builtin_amdgcn_s_setprio(1);                                       \
        _Pragma("unroll")                                                    \
        for (int mi = 0; mi < 4; ++mi)                                       \
            _Pragma("unroll")                                                \
            for (int ni = 0; ni < 4; ++ni)                                   \
                acc[4 + mi][ni] = __builtin_amdgcn_mfma_i32_16x16x64_i8(     \
                    af47[mi], bfr[ni], acc[4 + mi][ni], 0, 0, 0);            \
        __builtin_amdgcn_s_setprio(0);                                       \
        __builtin_amdgcn_s_barrier();                                        \
    }

    for (int kt = 0; kt < NPH / 4; ++kt) {
        const int kb = kt * 4;
        SUBA(0) SUBB(0)
        SUBA(1) SUBB(1)
        SUBA(2) SUBB(2)
        SUBA(3) SUBB(3)
    }
#undef SUBA
#undef SUBB

    // epilogue: per output row, argmax of (int dot * colS_j) over 256 j's
    const int jbase = jt * BM2 + wc * 64 + l15;
    float cs[4];
#pragma unroll
    for (int ni = 0; ni < 4; ++ni) {
        int j = jbase + ni * 16;
        cs[ni] = colS[j < LL ? j : 0];
    }
#pragma unroll
    for (int mi = 0; mi < 8; ++mi) {
#pragma unroll
        for (int rr = 0; rr < 4; ++rr) {
            float bv = -3.4e38f;
            int bj = 0x7FFFFFFF;
#pragma unroll
            for (int ni = 0; ni < 4; ++ni) {
                int j = jbase + ni * 16;
                float v = (float)acc[mi][ni][rr] * cs[ni];
                if (j < LL && (v > bv || (v == bv && j < bj))) { bv = v; bj = j; }
            }
#pragma unroll
            for (int m = 1; m < 16; m <<= 1) {
                float ov = __shfl_xor(bv, m, 64);
                int oj = __shfl_xor(bj, m, 64);
                if (ov > bv || (ov == bv && oj < bj)) { bv = ov; bj = oj; }
            }
            if (l15 == 0) {
                int i = it * BM2 + wr * 128 + mi * 16 + l4 * 4 + rr;
                if (i < LL) {
                    unsigned u = __float_as_uint(bv);
                    unsigned s = (bv < 0.f) ? ~u : (u | 0x80000000u);
                    u64 packed = ((u64)s << 32) | (unsigned)(~(unsigned)bj);
                    atomicMax(&best[i], packed);
                }
            }
        }
    }
}

// ---- 5: final scalar ----
__global__ __launch_bounds__(256) void k_final(const u64* __restrict__ best,
                                               const float* __restrict__ rnB,
                                               const float* __restrict__ n2B,
                                               const float* __restrict__ win2x,
                                               const float* __restrict__ sAf,
                                               float* __restrict__ out) {
    int i = blockIdx.x * 256 + threadIdx.x;
    float contrib = 0.f;
    if (i < LL) {
        u64 p = best[i];
        unsigned s = (unsigned)(p >> 32);
        unsigned ub = (s & 0x80000000u) ? (s & 0x7FFFFFFFu) : ~s;
        float bv = __uint_as_float(ub);             // = int_dot * colS_j
        int j = (int)(~(unsigned)(p & 0xFFFFFFFFull));
        float dot = (bv * sAf[i]) / rnB[j];         // = ip . sp_j
        contrib = win2x[i] + n2B[j] - 2.f * dot;
    }
    float sred = contrib;
#pragma unroll
    for (int o = 32; o > 0; o >>= 1) sred += __shfl_down(sred, o, 64);
    __shared__ float red[4];
    if ((threadIdx.x & 63) == 0) red[threadIdx.x >> 6] = sred;
    __syncthreads();
    if (threadIdx.x == 0) {
        float tot = red[0] + red[1] + red[2] + red[3];
        atomicAdd(out, tot * (1.0f / ((float)DD * (float)LL)));
    }
}

extern "C" void kernel_launch(void* const* d_in, const int* in_sizes, int n_in,
                              void* d_out, int out_size, void* d_ws, size_t ws_size,
                              hipStream_t stream) {
    const float* x  = (const float*)d_in[0];
    const float* st = (const float*)d_in[1];
    char* ws = (char*)d_ws;

    u8* Aq       = (u8*)ws;
    u8* Bq       = (u8*)(ws + OFF_BQ);
    float* rnB   = (float*)(ws + OFF_RNB);
    float* n2B   = (float*)(ws + OFF_N2B);
    float* win2x = (float*)(ws + OFF_W2X);
    float* qsA   = (float*)(ws + OFF_QSA);
    float* qsB   = (float*)(ws + OFF_QSB);
    float* colS  = (float*)(ws + OFF_COLS);
    float* sAf   = (float*)(ws + OFF_SAF);
    float* P2    = (float*)(ws + OFF_P2);
    float* PM    = (float*)(ws + OFF_PM);
    u64* best    = (u64*)(ws + OFF_BEST);
    float* out   = (float*)d_out;

    hipFuncSetAttribute((const void*)k_gemm2,
                        hipFuncAttributeMaxDynamicSharedMemorySize, 131072);

    hipMemsetAsync(best, 0, (size_t)LL * 8, stream);
    hipMemsetAsync(out, 0, sizeof(float), stream);

    k_chan_stats<<<dim3(72), dim3(256), 0, stream>>>(st, x, P2, PM);
    k_win<<<dim3(35), dim3(256), 0, stream>>>(P2, PM, rnB, n2B, win2x, qsA, qsB, colS, sAf);
    k_pack<<<dim3(2 * LPAD), dim3(256), 0, stream>>>(x, st, qsA, qsB, Aq, Bq);
    k_gemm2<<<dim3(NT2 * NT2), dim3(512), 131072, stream>>>(Aq, Bq, colS, best);
    k_final<<<dim3(35), dim3(256), 0, stream>>>(best, rnB, n2B, win2x, sAf, out);
}